// Round 1
// baseline (120.800 us; speedup 1.0000x reference)
//
#include <hip/hip_runtime.h>
#include <math.h>

#define NT 512      // threads (8 waves, single block, single CU)
#define EPT 8       // elements per thread (NT*EPT = 4096)
#define NN 4096
#define MM 9
#define NIT 50
#define CJ 5        // carry-gather terms; decay per hop = 2^-8, so error ~2^-40

// Reduce 9 per-thread partial sums across the block. dest[m*destStride] = sum (+1 if m==identCol).
__device__ __forceinline__ void block_reduce9(const float pq[MM], float* __restrict__ s_part,
                                              float* __restrict__ dest, int destStride,
                                              int identCol, int t) {
#pragma unroll
  for (int m = 0; m < MM; ++m) s_part[m * NT + t] = pq[m];
  __syncthreads();
  const int wave = t >> 6, lane = t & 63;
  for (int m = wave; m < MM; m += NT / 64) {
    float s = 0.f;
#pragma unroll
    for (int k = 0; k < NT / 64; ++k) s += s_part[m * NT + lane + 64 * k];
#pragma unroll
    for (int off = 32; off; off >>= 1) s += __shfl_xor(s, off, 64);
    if (lane == 0) dest[m * destStride] = s + ((m == identCol) ? 1.f : 0.f);
  }
  __syncthreads();
}

// Solve M p = r exactly (to ~2^-40), M = 25I - 10(P+P^T) = 5(2I-S+)(2I-S-).
// Backward pass: y[i] = r[i]/10 + y[i+1]/2 ; forward pass: p[i] = y[i]/2 + p[i-1]/2.
// Cyclic wrap + cross-thread carries resolved via truncated geometric gather (2^-8 per thread hop).
__device__ __forceinline__ void solveM(const float r[EPT], float p[EPT],
                                       float* __restrict__ s_lastA,
                                       float* __restrict__ s_lastB, int t) {
  float yl[EPT];
  yl[EPT - 1] = r[EPT - 1] * 0.1f;
#pragma unroll
  for (int j = EPT - 2; j >= 0; --j) yl[j] = fmaf(0.5f, yl[j + 1], r[j] * 0.1f);
  s_lastA[t] = yl[0];
  __syncthreads();
  float c = 0.f, wgt = 1.f;
#pragma unroll
  for (int j = 0; j < CJ; ++j) { c = fmaf(wgt, s_lastA[(t + 1 + j) & (NT - 1)], c); wgt *= (1.f / 256.f); }
  float y[EPT];
  float f = 0.5f;
#pragma unroll
  for (int j = EPT - 1; j >= 0; --j) { y[j] = fmaf(c, f, yl[j]); f *= 0.5f; }
  float pl[EPT];
  pl[0] = 0.5f * y[0];
#pragma unroll
  for (int j = 1; j < EPT; ++j) pl[j] = 0.5f * (y[j] + pl[j - 1]);
  s_lastB[t] = pl[EPT - 1];
  __syncthreads();
  float c2 = 0.f, w2 = 1.f;
#pragma unroll
  for (int j = 0; j < CJ; ++j) { c2 = fmaf(w2, s_lastB[(t + NT - 1 - j) & (NT - 1)], c2); w2 *= (1.f / 256.f); }
  float f2 = 0.5f;
#pragma unroll
  for (int j = 0; j < EPT; ++j) { p[j] = fmaf(c2, f2, pl[j]); f2 *= 0.5f; }
}

__global__ void __launch_bounds__(NT)
admm_kernel(const float* __restrict__ tg, const float* __restrict__ Ag,
            const float* __restrict__ x0, float* __restrict__ out) {
  __shared__ float s_x[NN];
  __shared__ float s_part[MM * NT];
  __shared__ float s_lastA[NT];
  __shared__ float s_lastB[NT];
  __shared__ float s_q[MM];
  __shared__ float s_z[MM];
  __shared__ float s_S[MM * MM];
  __shared__ float s_Sinv[MM * MM];

  const int t = threadIdx.x;
  const int base = t * EPT;

  // ---- load A slice (columns base..base+7 of all 9 rows) into registers ----
  float A[MM][EPT];
#pragma unroll
  for (int m = 0; m < MM; ++m) {
    float4 a0 = *(const float4*)(Ag + m * NN + base);
    float4 a1 = *(const float4*)(Ag + m * NN + base + 4);
    A[m][0] = a0.x; A[m][1] = a0.y; A[m][2] = a0.z; A[m][3] = a0.w;
    A[m][4] = a1.x; A[m][5] = a1.y; A[m][6] = a1.z; A[m][7] = a1.w;
  }

  // ---- load x0 and target ----
  float x[EPT], tgt[EPT];
  {
    float4 v0 = *(const float4*)(x0 + base);
    float4 v1 = *(const float4*)(x0 + base + 4);
    x[0] = v0.x; x[1] = v0.y; x[2] = v0.z; x[3] = v0.w;
    x[4] = v1.x; x[5] = v1.y; x[6] = v1.z; x[7] = v1.w;
    float4 t0 = *(const float4*)(tg + base);
    float4 t1 = *(const float4*)(tg + base + 4);
    tgt[0] = t0.x; tgt[1] = t0.y; tgt[2] = t0.z; tgt[3] = t0.w;
    tgt[4] = t1.x; tgt[5] = t1.y; tgt[6] = t1.z; tgt[7] = t1.w;
  }
#pragma unroll
  for (int j = 0; j < EPT; ++j) s_x[base + j] = x[j];

  // ---- b = A @ target (9 block reductions) ----
  float pq[MM];
#pragma unroll
  for (int m = 0; m < MM; ++m) {
    float s = 0.f;
#pragma unroll
    for (int j = 0; j < EPT; ++j) s = fmaf(A[m][j], tgt[j], s);
    pq[m] = s;
  }
  block_reduce9(pq, s_part, s_q, 1, -1, t);

  // ---- bA = b @ A (per-thread) ----
  float bA[EPT];
  {
    float bv[MM];
#pragma unroll
    for (int m = 0; m < MM; ++m) bv[m] = s_q[m];
#pragma unroll
    for (int j = 0; j < EPT; ++j) {
      float s = 0.f;
#pragma unroll
      for (int m = 0; m < MM; ++m) s = fmaf(bv[m], A[m][j], s);
      bA[j] = s;
    }
  }

  // ---- G = M^-1 A^T, one column per A-row, via scans ----
  float G[MM][EPT];
#pragma unroll
  for (int m = 0; m < MM; ++m) {
    float rin[EPT], pcol[EPT];
#pragma unroll
    for (int j = 0; j < EPT; ++j) rin[j] = A[m][j];
    solveM(rin, pcol, s_lastA, s_lastB, t);
#pragma unroll
    for (int j = 0; j < EPT; ++j) G[m][j] = pcol[j];
  }

  // ---- S = I9 + A G  (one column per round) ----
#pragma unroll
  for (int mcol = 0; mcol < MM; ++mcol) {
#pragma unroll
    for (int k = 0; k < MM; ++k) {
      float s = 0.f;
#pragma unroll
      for (int j = 0; j < EPT; ++j) s = fmaf(A[k][j], G[mcol][j], s);
      pq[k] = s;
    }
    block_reduce9(pq, s_part, &s_S[mcol], MM, mcol, t);
  }

  // ---- invert S (9x9, SPD) via wave-parallel Gauss-Jordan, lanes 0..8 own rows ----
  if (t < 64) {
    float row[2 * MM];
#pragma unroll
    for (int j = 0; j < MM; ++j) row[j] = (t < MM) ? s_S[t * MM + j] : 0.f;
#pragma unroll
    for (int j = 0; j < MM; ++j) row[MM + j] = (j == t) ? 1.f : 0.f;
#pragma unroll
    for (int pp = 0; pp < MM; ++pp) {
      float pr[2 * MM];
#pragma unroll
      for (int j = 0; j < 2 * MM; ++j) pr[j] = __shfl(row[j], pp, 64);
      float rpiv = 1.f / pr[pp];
      float fct = row[pp] * rpiv;
#pragma unroll
      for (int j = 0; j < 2 * MM; ++j)
        row[j] = (t == pp) ? pr[j] * rpiv : fmaf(-fct, pr[j], row[j]);
    }
    if (t < MM) {
#pragma unroll
      for (int j = 0; j < MM; ++j) s_Sinv[t * MM + j] = row[MM + j];
    }
  }
  __syncthreads();

  // ---- ADMM iterations ----
  float eta[EPT], tau[EPT];
#pragma unroll
  for (int j = 0; j < EPT; ++j) { eta[j] = 0.f; tau[j] = 0.f; }

#pragma unroll 1
  for (int it = 0; it < NIT; ++it) {
    // elementwise: u_tv, w, resid (x[i-1] via LDS at segment boundary)
    float xm1 = s_x[(base + NN - 1) & (NN - 1)];
    float u[EPT], w[EPT], r[EPT];
#pragma unroll
    for (int j = 0; j < EPT; ++j) {
      float xprev = (j == 0) ? xm1 : x[j - 1];
      float v = xprev - x[j] + eta[j] * 0.1f;
      float a = fabsf(v) - 1e-5f;
      u[j] = (a > 0.f) ? copysignf(a, v) : 0.f;
      w[j] = fmaxf(fmaf(tau[j], 0.2f, x[j]), 0.f);
      r[j] = bA[j] + 10.f * u[j] - eta[j] + 5.f * w[j] - tau[j];
    }
    // p = M^-1 r
    float p[EPT];
    solveM(r, p, s_lastA, s_lastB, t);
    // q = A p
#pragma unroll
    for (int m = 0; m < MM; ++m) {
      float s = 0.f;
#pragma unroll
      for (int j = 0; j < EPT; ++j) s = fmaf(A[m][j], p[j], s);
      pq[m] = s;
    }
    block_reduce9(pq, s_part, s_q, 1, -1, t);
    // z = Sinv q (lanes 0..8)
    if (t < MM) {
      float s = 0.f;
#pragma unroll
      for (int k = 0; k < MM; ++k) s = fmaf(s_Sinv[t * MM + k], s_q[k], s);
      s_z[t] = s;
    }
    __syncthreads();
    // x_new = p - G z  (Woodbury correction)
    float zz[MM];
#pragma unroll
    for (int m = 0; m < MM; ++m) zz[m] = s_z[m];
    float xn[EPT];
#pragma unroll
    for (int j = 0; j < EPT; ++j) {
      float s = p[j];
#pragma unroll
      for (int m = 0; m < MM; ++m) s = fmaf(-G[m][j], zz[m], s);
      xn[j] = s;
    }
#pragma unroll
    for (int j = 0; j < EPT; ++j) s_x[base + j] = xn[j];
    __syncthreads();
    // dual updates (need x_new[i+1] at segment boundary)
    float xnext = s_x[(base + EPT) & (NN - 1)];
#pragma unroll
    for (int j = 0; j < EPT; ++j) {
      float d = ((j == EPT - 1) ? xnext : xn[j + 1]) - xn[j];
      eta[j] = fmaf(10.f, d - u[j], eta[j]);
      tau[j] = fmaf(5.f, xn[j] - w[j], tau[j]);
      x[j] = xn[j];
    }
  }

  // ---- output ----
  float4 o0, o1;
  o0.x = x[0]; o0.y = x[1]; o0.z = x[2]; o0.w = x[3];
  o1.x = x[4]; o1.y = x[5]; o1.z = x[6]; o1.w = x[7];
  *(float4*)(out + base) = o0;
  *(float4*)(out + base + 4) = o1;
}

extern "C" void kernel_launch(void* const* d_in, const int* in_sizes, int n_in,
                              void* d_out, int out_size, void* d_ws, size_t ws_size,
                              hipStream_t stream) {
  const float* target = (const float*)d_in[0];
  const float* A      = (const float*)d_in[1];
  const float* x0     = (const float*)d_in[2];
  admm_kernel<<<1, NT, 0, stream>>>(target, A, x0, (float*)d_out);
}